// Round 1
// baseline (4720.280 us; speedup 1.0000x reference)
//
#include <hip/hip_runtime.h>
#include <math.h>

#define NN 102400
#define FD 128
#define KC 16
#define BG 64
#define NPG 1600
#define NE 3276800
#define PART_STRIDE 16384

__device__ __forceinline__ void lds_addf(float* p, float v) {
  __hip_atomic_fetch_add(p, v, __ATOMIC_RELAXED, __HIP_MEMORY_SCOPE_WORKGROUP);
}
__device__ __forceinline__ void glob_addf(float* p, float v) {
  unsafeAtomicAdd(p, v);
}

// -------------------- s = softmax(softmax(x@W+b)) + deg scatter --------------------
__global__ __launch_bounds__(256) void k_s(const float* __restrict__ x,
    const float* __restrict__ W, const float* __restrict__ bb,
    const float* __restrict__ ew, const int* __restrict__ edst,
    float* __restrict__ s, float* __restrict__ deg) {
  const int t = threadIdx.x;
  const int n = blockIdx.x * 256 + t;
  float acc[KC];
#pragma unroll
  for (int k = 0; k < KC; ++k) acc[k] = bb[k];
  const float4* xr = (const float4*)(x + (size_t)n * FD);
#pragma unroll 4
  for (int c = 0; c < FD / 4; ++c) {
    float4 v = xr[c];
    const float* wr = W + c * 4 * KC;   // wave-uniform -> scalar loads
#pragma unroll
    for (int k = 0; k < KC; ++k)
      acc[k] += v.x * wr[k] + v.y * wr[KC + k] + v.z * wr[2 * KC + k] + v.w * wr[3 * KC + k];
  }
#pragma unroll
  for (int r = 0; r < 2; ++r) {
    float m = acc[0];
#pragma unroll
    for (int k = 1; k < KC; ++k) m = fmaxf(m, acc[k]);
    float sum = 0.f;
#pragma unroll
    for (int k = 0; k < KC; ++k) { acc[k] = expf(acc[k] - m); sum += acc[k]; }
    float inv = 1.f / sum;
#pragma unroll
    for (int k = 0; k < KC; ++k) acc[k] *= inv;
  }
  float4* so = (float4*)(s + (size_t)n * KC);
  so[0] = make_float4(acc[0], acc[1], acc[2], acc[3]);
  so[1] = make_float4(acc[4], acc[5], acc[6], acc[7]);
  so[2] = make_float4(acc[8], acc[9], acc[10], acc[11]);
  so[3] = make_float4(acc[12], acc[13], acc[14], acc[15]);
  // deg[dst] += w  (grid-stride over edges)
  for (int e = n; e < NE; e += NN) glob_addf(deg + edst[e], ew[e]);
}

// -------------------- out_adj partials: sum_e w * s_src (x) s_dst --------------------
__global__ __launch_bounds__(1024) void k_edge(const float* __restrict__ s,
    const float* __restrict__ ew, const int* __restrict__ esrc,
    const int* __restrict__ edst, float* __restrict__ part, int nblk) {
  __shared__ float acc[BG * 256];   // exactly 64 KB
  const int t = threadIdx.x;
  for (int i = t; i < BG * 256; i += 1024) acc[i] = 0.f;
  __syncthreads();
  const int lane = t & 63;
  const int k = lane & 15, q = lane >> 4;
  const int koff = k * 16 + q * 4;
  const int wv_id = (blockIdx.x << 4) + (t >> 6);
  const int nwaves = nblk << 4;
  const int nbatch = NE >> 6;       // 51200, exact
  for (int bt = wv_id; bt < nbatch; bt += nwaves) {
    const int base = (bt << 6) + lane;
    float wv = ew[base];
    int sv = esrc[base];
    int dv = edst[base];
#pragma unroll 8
    for (int e = 0; e < 64; ++e) {
      float we = __int_as_float(__builtin_amdgcn_readlane(__float_as_int(wv), e));
      int ss = __builtin_amdgcn_readlane(sv, e);
      int dd = __builtin_amdgcn_readlane(dv, e);
      int g = (int)((unsigned)ss / (unsigned)NPG);
      float a = s[ss * KC + k];                                // 16 words, scalar base
      const float4 b4 = *(const float4*)(s + dd * KC + q * 4); // dwordx4, scalar base
      float wa = we * a;
      float* ap = acc + g * 256 + koff;
      lds_addf(ap + 0, wa * b4.x);
      lds_addf(ap + 1, wa * b4.y);
      lds_addf(ap + 2, wa * b4.z);
      lds_addf(ap + 3, wa * b4.w);
    }
  }
  __syncthreads();
  float* dst = part + (size_t)blockIdx.x * PART_STRIDE;
  for (int i = t; i < PART_STRIDE; i += 1024) dst[i] = acc[i];
}

// -------------------- partial reduce + per-graph node pass (CC, out_x, den) --------------------
__global__ __launch_bounds__(256) void k_mid(const float* __restrict__ s,
    const float* __restrict__ x, const float* __restrict__ deg,
    const float* __restrict__ part, float* __restrict__ adj_raw,
    float* __restrict__ cc_raw, float* __restrict__ outx_raw,
    float* __restrict__ den, int nblk) {
  const int t = threadIdx.x;
  __shared__ float st[80 * KC];
  __shared__ float dt[80];
  __shared__ float scr[4];
  if (blockIdx.x < 64) {            // reduce out_adj partials
    const int idx = blockIdx.x * 256 + t;
    float sum = 0.f;
    for (int p = 0; p < nblk; ++p) sum += part[(size_t)p * PART_STRIDE + idx];
    adj_raw[idx] = sum;
    return;
  }
  const int nb = blockIdx.x - 64;   // 0..255 : 4 blocks per graph
  const int g = nb >> 2, sub = nb & 3;
  const int n0 = g * NPG + sub * 400;
  const int j = t & 127, h = t >> 7;
  const int kc = t >> 4, lc = t & 15;
  float accX[8] = {0.f, 0.f, 0.f, 0.f, 0.f, 0.f, 0.f, 0.f};
  float accC = 0.f, accD = 0.f;
  for (int i0 = 0; i0 < 400; i0 += 80) {
    __syncthreads();
    for (int u = t; u < 80 * KC; u += 256) st[u] = s[(size_t)(n0 + i0) * KC + u];
    if (t < 80) dt[t] = deg[n0 + i0 + t];
    __syncthreads();
    for (int i = 0; i < 80; ++i) {
      const float xv = x[(size_t)(n0 + i0 + i) * FD + j];
      const float* si = st + i * KC;
#pragma unroll
      for (int kk = 0; kk < 8; ++kk) accX[kk] += si[h * 8 + kk] * xv;
      const float ck = si[kc], cl = si[lc];
      accC += ck * cl;
      accD += dt[i] * cl * cl;      // 16 copies of each k -> scale 1/16 below
    }
  }
#pragma unroll
  for (int kk = 0; kk < 8; ++kk)
    glob_addf(outx_raw + g * 2048 + (h * 8 + kk) * 128 + j, accX[kk]);
  glob_addf(cc_raw + g * 256 + t, accC);
  __syncthreads();
#pragma unroll
  for (int o = 32; o > 0; o >>= 1) accD += __shfl_down(accD, o, 64);
  if ((t & 63) == 0) scr[t >> 6] = accD;
  __syncthreads();
  if (t == 0) glob_addf(den, (scr[0] + scr[1] + scr[2] + scr[3]) * (1.f / 16.f));
}

// -------------------- finalize: adj normalize, trace, ortho, SELU --------------------
__device__ __forceinline__ float bred(float v, float* scr) {
#pragma unroll
  for (int o = 32; o > 0; o >>= 1) v += __shfl_down(v, o, 64);
  __syncthreads();
  if ((threadIdx.x & 63) == 0) scr[threadIdx.x >> 6] = v;
  __syncthreads();
  return scr[0] + scr[1] + scr[2] + scr[3];
}

__global__ __launch_bounds__(256) void k_post(const float* __restrict__ adj_raw,
    const float* __restrict__ cc_raw, const float* __restrict__ outx_raw,
    float* __restrict__ out, float* __restrict__ ws_num, float* __restrict__ ws_ortho) {
  const int b = blockIdx.x, t = threadIdx.x;
  const int k = t >> 4, l = t & 15;
  __shared__ float m[16 * 17];
  __shared__ float dk[16];
  __shared__ float scr[4];
  const float raw = adj_raw[b * 256 + t];
  const float masked = (k == l) ? 0.f : raw;
  m[k * 17 + l] = masked;
  __syncthreads();
  if (t < 16) {
    float rs = 0.f;
#pragma unroll
    for (int ll = 0; ll < 16; ++ll) rs += m[t * 17 + ll];
    dk[t] = sqrtf(rs) + 1e-12f;
  }
  __syncthreads();
  out[131072 + b * 256 + t] = masked / (dk[k] * dk[l]);
  float tr = bred((k == l) ? raw : 0.f, scr);
  if (t == 0) glob_addf(ws_num, tr);
  const float c = cc_raw[b * 256 + t];
  float n2 = bred(c * c, scr);
  float diff = c / sqrtf(n2) - ((k == l) ? 0.25f : 0.f);
  float d2 = bred(diff * diff, scr);
  if (t == 0) glob_addf(ws_ortho, sqrtf(d2));
  // SELU over out_x
  for (int idx = b * 256 + t; idx < 131072; idx += 16384) {
    float xv = outx_raw[idx];
    out[idx] = xv > 0.f ? 1.0507009873554805f * xv
                        : 1.0507009873554805f * 1.6732632423543772f * expm1f(xv);
  }
}

__global__ void k_last(const float* __restrict__ scal, float* __restrict__ out) {
  out[147456] = -scal[1] / scal[0];      // -num/den
  out[147457] = scal[2] * (1.f / 64.f);  // mean ortho
}

// -------------------- launch --------------------
extern "C" void kernel_launch(void* const* d_in, const int* in_sizes, int n_in,
                              void* d_out, int out_size, void* d_ws, size_t ws_size,
                              hipStream_t stream) {
  const float* x  = (const float*)d_in[0];
  const float* W  = (const float*)d_in[1];
  const float* bb = (const float*)d_in[2];
  const float* ew = (const float*)d_in[3];
  const int* esrc = (const int*)d_in[4];
  const int* edst = (const int*)d_in[5];
  float* out = (float*)d_out;
  float* ws = (float*)d_ws;

  float* s_buf   = ws;                    // 1,638,400 floats
  float* adj_raw = s_buf + (size_t)NN * KC;
  float* deg     = adj_raw + 16384;
  float* cc_raw  = deg + NN;
  float* outx    = cc_raw + 16384;
  float* scal    = outx + 131072;         // [0]=den [1]=num [2]=ortho
  float* part    = scal + 4;

  size_t fixed_floats = (size_t)(part - ws);
  int eblk = 512;
  size_t avail = ws_size / 4;
  if (avail > fixed_floats) {
    size_t cap = (avail - fixed_floats) / PART_STRIDE;
    if ((size_t)eblk > cap) eblk = (int)cap;
  } else {
    eblk = 64;
  }
  if (eblk < 64) eblk = 64;
  if (eblk > 512) eblk = 512;

  hipMemsetAsync(deg, 0, (size_t)(NN + 16384 + 131072 + 4) * sizeof(float), stream);
  k_s<<<NN / 256, 256, 0, stream>>>(x, W, bb, ew, edst, s_buf, deg);
  k_edge<<<eblk, 1024, 0, stream>>>(s_buf, ew, esrc, edst, part, eblk);
  k_mid<<<320, 256, 0, stream>>>(s_buf, x, deg, part, adj_raw, cc_raw, outx, scal, eblk);
  k_post<<<64, 256, 0, stream>>>(adj_raw, cc_raw, outx, out, scal + 1, scal + 2);
  k_last<<<1, 1, 0, stream>>>(scal, out);
}

// Round 2
// 431.910 us; speedup vs baseline: 10.9288x; 10.9288x over previous
//
#include <hip/hip_runtime.h>
#include <math.h>

#define NN 102400
#define FD 128
#define KC 16
#define BG 64
#define NPG 1600
#define NE 3276800
#define HB 1024          // hist/scatter blocks
#define EH (NE / HB)     // 3200 edges per hist/scatter block
#define EPB 16           // k_edge blocks per graph

__device__ __forceinline__ void glob_addf(float* p, float v) {
  unsafeAtomicAdd(p, v);
}

// -------------------- s = softmax(softmax(x@W+b)) --------------------
__global__ __launch_bounds__(256) void k_s(const float* __restrict__ x,
    const float* __restrict__ W, const float* __restrict__ bb,
    float* __restrict__ s) {
  const int t = threadIdx.x;
  const int n = blockIdx.x * 256 + t;
  float acc[KC];
#pragma unroll
  for (int k = 0; k < KC; ++k) acc[k] = bb[k];
  const float4* xr = (const float4*)(x + (size_t)n * FD);
#pragma unroll 4
  for (int c = 0; c < FD / 4; ++c) {
    float4 v = xr[c];
    const float* wr = W + c * 4 * KC;
#pragma unroll
    for (int k = 0; k < KC; ++k)
      acc[k] += v.x * wr[k] + v.y * wr[KC + k] + v.z * wr[2 * KC + k] + v.w * wr[3 * KC + k];
  }
#pragma unroll
  for (int r = 0; r < 2; ++r) {
    float m = acc[0];
#pragma unroll
    for (int k = 1; k < KC; ++k) m = fmaxf(m, acc[k]);
    float sum = 0.f;
#pragma unroll
    for (int k = 0; k < KC; ++k) { acc[k] = expf(acc[k] - m); sum += acc[k]; }
    float inv = 1.f / sum;
#pragma unroll
    for (int k = 0; k < KC; ++k) acc[k] *= inv;
  }
  float4* so = (float4*)(s + (size_t)n * KC);
  so[0] = make_float4(acc[0], acc[1], acc[2], acc[3]);
  so[1] = make_float4(acc[4], acc[5], acc[6], acc[7]);
  so[2] = make_float4(acc[8], acc[9], acc[10], acc[11]);
  so[3] = make_float4(acc[12], acc[13], acc[14], acc[15]);
}

// -------------------- counting sort by graph: histogram --------------------
__global__ __launch_bounds__(256) void k_hist(const int* __restrict__ esrc,
    unsigned* __restrict__ blkhist) {
  __shared__ unsigned h[BG];
  const int t = threadIdx.x, b = blockIdx.x;
  if (t < BG) h[t] = 0u;
  __syncthreads();
  const int e0 = b * EH;
  for (int i = t; i < EH; i += 256) {
    unsigned g = (unsigned)esrc[e0 + i] / (unsigned)NPG;
    atomicAdd(&h[g], 1u);           // direct __shared__ index -> ds_add_u32
  }
  __syncthreads();
  if (t < BG) blkhist[t * HB + b] = h[t];
}

// -------------------- scan: per-(graph,block) offsets + bucket bases --------------------
__global__ void k_scan(unsigned* __restrict__ blkhist, unsigned* __restrict__ gbase) {
  __shared__ unsigned tot[BG];
  const int g = threadIdx.x;   // 64 threads
  unsigned run = 0;
#pragma unroll 8
  for (int b = 0; b < HB; ++b) {
    unsigned c = blkhist[g * HB + b];
    blkhist[g * HB + b] = run;
    run += c;
  }
  tot[g] = run;
  __syncthreads();
  if (g == 0) {
    unsigned base = 0;
    for (int gg = 0; gg < BG; ++gg) { gbase[gg] = base; base += tot[gg]; }
    gbase[BG] = base;  // == NE
  }
}

// -------------------- scatter edges into per-graph buckets --------------------
__global__ __launch_bounds__(256) void k_scatter(const float* __restrict__ ew,
    const int* __restrict__ esrc, const int* __restrict__ edst,
    const unsigned* __restrict__ blkhist, const unsigned* __restrict__ gbase,
    float* __restrict__ sw, unsigned* __restrict__ spk) {
  __shared__ unsigned h[BG];
  __shared__ unsigned off[BG];
  const int t = threadIdx.x, b = blockIdx.x;
  if (t < BG) { h[t] = 0u; off[t] = gbase[t] + blkhist[t * HB + b]; }
  __syncthreads();
  const int e0 = b * EH;
  for (int i = t; i < EH; i += 256) {
    int e = e0 + i;
    int s0 = esrc[e], d0 = edst[e];
    float w = ew[e];
    unsigned g = (unsigned)s0 / (unsigned)NPG;
    unsigned r = atomicAdd(&h[g], 1u);
    unsigned pos = off[g] + r;
    sw[pos] = w;
    spk[pos] = (unsigned)(s0 - (int)g * NPG) | ((unsigned)(d0 - (int)g * NPG) << 11);
  }
}

// -------------------- out_adj: sum_e w * s_src (x) s_dst, register accumulation --------------------
__global__ __launch_bounds__(256, 4) void k_edge2(const float* __restrict__ s,
    const float* __restrict__ sw, const unsigned* __restrict__ spk,
    const unsigned* __restrict__ gbase, float* __restrict__ adj_raw) {
  __shared__ float red[4 * 256];
  const int t = threadIdx.x;
  const int g = blockIdx.x & 63;          // same-graph blocks share an XCD (bid%8 pattern)
  const int sub = blockIdx.x >> 6;        // 0..EPB-1
  const int lane = t & 63, w = t >> 6;
  const int k = lane & 15, q4 = (lane >> 4) * 4;
  const unsigned beg = gbase[g], end = gbase[g + 1];
  const unsigned cnt = end - beg;
  const unsigned nb = (cnt + 63u) >> 6;
  const int wid = sub * 4 + w;            // 0..63 waves per graph
  const float* sG = s + (size_t)g * NPG * KC;
  float a0 = 0.f, a1 = 0.f, a2 = 0.f, a3 = 0.f;
  for (unsigned bt = wid; bt < nb; bt += EPB * 4) {
    unsigned idx = beg + (bt << 6) + (unsigned)lane;
    bool ok = idx < end;
    float wv = ok ? sw[idx] : 0.f;
    unsigned pv = ok ? spk[idx] : 0u;
#pragma unroll 8
    for (int e = 0; e < 64; ++e) {
      float we = __int_as_float(__builtin_amdgcn_readlane(__float_as_int(wv), e));
      unsigned pk = (unsigned)__builtin_amdgcn_readlane((int)pv, e);
      int sl = (int)(pk & 0x7FFu), dl = (int)(pk >> 11);
      float a = sG[sl * KC + k];
      const float4 b4 = *(const float4*)(sG + dl * KC + q4);
      float wa = we * a;
      a0 = fmaf(wa, b4.x, a0);
      a1 = fmaf(wa, b4.y, a1);
      a2 = fmaf(wa, b4.z, a2);
      a3 = fmaf(wa, b4.w, a3);
    }
  }
  const int koff = k * 16 + q4;
  red[w * 256 + koff + 0] = a0;
  red[w * 256 + koff + 1] = a1;
  red[w * 256 + koff + 2] = a2;
  red[w * 256 + koff + 3] = a3;
  __syncthreads();
  float sum = red[t] + red[256 + t] + red[512 + t] + red[768 + t];
  glob_addf(adj_raw + g * 256 + t, sum);
}

// -------------------- mincut denominator: sum_e w_e * ||s_dst||^2 --------------------
__global__ __launch_bounds__(256) void k_den(const float* __restrict__ s,
    const float* __restrict__ sw, const unsigned* __restrict__ spk,
    const unsigned* __restrict__ gbase, float* __restrict__ den) {
  __shared__ float scr[4];
  const int t = threadIdx.x;
  const int g = blockIdx.x & 63, sub = blockIdx.x >> 6;  // 4 blocks/graph
  const unsigned beg = gbase[g], end = gbase[g + 1];
  const float* sG = s + (size_t)g * NPG * KC;
  float dacc = 0.f;
  for (unsigned i = beg + sub * 256u + (unsigned)t; i < end; i += 1024u) {
    float w = sw[i];
    int dl = (int)(spk[i] >> 11);
    const float4* r = (const float4*)(sG + dl * KC);
    float4 r0 = r[0], r1 = r[1], r2 = r[2], r3 = r[3];
    float d = r0.x * r0.x + r0.y * r0.y + r0.z * r0.z + r0.w * r0.w
            + r1.x * r1.x + r1.y * r1.y + r1.z * r1.z + r1.w * r1.w
            + r2.x * r2.x + r2.y * r2.y + r2.z * r2.z + r2.w * r2.w
            + r3.x * r3.x + r3.y * r3.y + r3.z * r3.z + r3.w * r3.w;
    dacc = fmaf(w, d, dacc);
  }
#pragma unroll
  for (int o = 32; o > 0; o >>= 1) dacc += __shfl_down(dacc, o, 64);
  if ((t & 63) == 0) scr[t >> 6] = dacc;
  __syncthreads();
  if (t == 0) glob_addf(den, scr[0] + scr[1] + scr[2] + scr[3]);
}

// -------------------- per-graph node pass: CC and out_x --------------------
__global__ __launch_bounds__(256) void k_mid(const float* __restrict__ s,
    const float* __restrict__ x, float* __restrict__ cc_raw,
    float* __restrict__ outx_raw) {
  const int t = threadIdx.x;
  __shared__ float st[80 * KC];
  const int g = blockIdx.x >> 2, sub = blockIdx.x & 3;
  const int n0 = g * NPG + sub * 400;
  const int j = t & 127, h = t >> 7;
  const int kc = t >> 4, lc = t & 15;
  float accX[8] = {0.f, 0.f, 0.f, 0.f, 0.f, 0.f, 0.f, 0.f};
  float accC = 0.f;
  for (int i0 = 0; i0 < 400; i0 += 80) {
    __syncthreads();
    for (int u = t; u < 80 * KC; u += 256) st[u] = s[(size_t)(n0 + i0) * KC + u];
    __syncthreads();
    for (int i = 0; i < 80; ++i) {
      const float xv = x[(size_t)(n0 + i0 + i) * FD + j];
      const float* si = st + i * KC;
#pragma unroll
      for (int kk = 0; kk < 8; ++kk) accX[kk] += si[h * 8 + kk] * xv;
      accC += si[kc] * si[lc];
    }
  }
#pragma unroll
  for (int kk = 0; kk < 8; ++kk)
    glob_addf(outx_raw + g * 2048 + (h * 8 + kk) * 128 + j, accX[kk]);
  glob_addf(cc_raw + g * 256 + t, accC);
}

// -------------------- finalize: adj normalize, trace, ortho, SELU --------------------
__device__ __forceinline__ float bred(float v, float* scr) {
#pragma unroll
  for (int o = 32; o > 0; o >>= 1) v += __shfl_down(v, o, 64);
  __syncthreads();
  if ((threadIdx.x & 63) == 0) scr[threadIdx.x >> 6] = v;
  __syncthreads();
  return scr[0] + scr[1] + scr[2] + scr[3];
}

__global__ __launch_bounds__(256) void k_post(const float* __restrict__ adj_raw,
    const float* __restrict__ cc_raw, const float* __restrict__ outx_raw,
    float* __restrict__ out, float* __restrict__ ws_num, float* __restrict__ ws_ortho) {
  const int b = blockIdx.x, t = threadIdx.x;
  const int k = t >> 4, l = t & 15;
  __shared__ float m[16 * 17];
  __shared__ float dk[16];
  __shared__ float scr[4];
  const float raw = adj_raw[b * 256 + t];
  const float masked = (k == l) ? 0.f : raw;
  m[k * 17 + l] = masked;
  __syncthreads();
  if (t < 16) {
    float rs = 0.f;
#pragma unroll
    for (int ll = 0; ll < 16; ++ll) rs += m[t * 17 + ll];
    dk[t] = sqrtf(rs) + 1e-12f;
  }
  __syncthreads();
  out[131072 + b * 256 + t] = masked / (dk[k] * dk[l]);
  float tr = bred((k == l) ? raw : 0.f, scr);
  if (t == 0) glob_addf(ws_num, tr);
  const float c = cc_raw[b * 256 + t];
  float n2 = bred(c * c, scr);
  float diff = c / sqrtf(n2) - ((k == l) ? 0.25f : 0.f);
  float d2 = bred(diff * diff, scr);
  if (t == 0) glob_addf(ws_ortho, sqrtf(d2));
  for (int idx = b * 256 + t; idx < 131072; idx += 16384) {
    float xv = outx_raw[idx];
    out[idx] = xv > 0.f ? 1.0507009873554805f * xv
                        : 1.0507009873554805f * 1.6732632423543772f * expm1f(xv);
  }
}

__global__ void k_last(const float* __restrict__ scal, float* __restrict__ out) {
  out[147456] = -scal[1] / scal[0];      // -num/den
  out[147457] = scal[2] * (1.f / 64.f);  // mean ortho
}

// -------------------- launch --------------------
extern "C" void kernel_launch(void* const* d_in, const int* in_sizes, int n_in,
                              void* d_out, int out_size, void* d_ws, size_t ws_size,
                              hipStream_t stream) {
  const float* x  = (const float*)d_in[0];
  const float* W  = (const float*)d_in[1];
  const float* bb = (const float*)d_in[2];
  const float* ew = (const float*)d_in[3];
  const int* esrc = (const int*)d_in[4];
  const int* edst = (const int*)d_in[5];
  float* out = (float*)d_out;
  float* ws = (float*)d_ws;

  float* s_buf   = ws;                                   // 1,638,400 f
  float* adj_raw = s_buf + (size_t)NN * KC;              // 16,384 f
  float* cc_raw  = adj_raw + 16384;                      // 16,384 f
  float* outx    = cc_raw + 16384;                       // 131,072 f
  float* scal    = outx + 131072;                        // 4 f: [0]=den [1]=num [2]=ortho
  unsigned* blkhist = (unsigned*)(scal + 4);             // 65,536 u
  unsigned* gbase   = blkhist + (size_t)BG * HB;         // 65 u
  float* sw      = (float*)(gbase + 68);                 // NE f   (align pad)
  unsigned* spk  = (unsigned*)(sw + NE);                 // NE u
  // total ~= 33.8 MB (< 41 MB proven available last round)

  hipMemsetAsync(adj_raw, 0, (size_t)(16384 + 16384 + 131072 + 4) * sizeof(float), stream);
  k_s<<<NN / 256, 256, 0, stream>>>(x, W, bb, s_buf);
  k_hist<<<HB, 256, 0, stream>>>(esrc, blkhist);
  k_scan<<<1, 64, 0, stream>>>(blkhist, gbase);
  k_scatter<<<HB, 256, 0, stream>>>(ew, esrc, edst, blkhist, gbase, sw, spk);
  k_edge2<<<BG * EPB, 256, 0, stream>>>(s_buf, sw, spk, gbase, adj_raw);
  k_den<<<BG * 4, 256, 0, stream>>>(s_buf, sw, spk, gbase, scal);
  k_mid<<<BG * 4, 256, 0, stream>>>(s_buf, x, cc_raw, outx);
  k_post<<<64, 256, 0, stream>>>(adj_raw, cc_raw, outx, out, scal + 1, scal + 2);
  k_last<<<1, 1, 0, stream>>>(scal, out);
}